// Round 4
// baseline (398.816 us; speedup 1.0000x reference)
//
#include <hip/hip_runtime.h>
#include <math.h>

#define NPTS 120000
#define NLID 100000
#define NRAD 20000
#define NTOT (2 * NPTS)
#define MAPW 512
#define MAPHW (512 * 512)
#define NTILES 8192

typedef short sh8 __attribute__((ext_vector_type(8)));
typedef float f32x4 __attribute__((ext_vector_type(4)));
typedef unsigned short u16;
typedef unsigned int u32;

// bf16 feature tile: feat[192 ch][64 px], row stride CSTR u16.
// CSTR=70 (140 B, 35 dwords, odd) -> staging b32-pair writes 2-way (free) and
// A-build u16 reads conflict-free (32 distinct banks, pairs share dwords).
#define CSTR 70
#define H1S 72
#define H2S 40
#define H3S 24
#define HWAVE (16 * (H1S + H2S + H3S))    // 2176 u16 per wave

__device__ __forceinline__ float gelu_f(float x) {
    return 0.5f * x * (1.0f + erff(x * 0.7071067811865476f));
}
__device__ __forceinline__ u16 f2bf(float f) {  // RNE
    unsigned int u = __float_as_uint(f);
    return (u16)((u + 0x7FFFu + ((u >> 16) & 1u)) >> 16);
}
__device__ __forceinline__ float bf2f(u16 h) {
    return __uint_as_float((unsigned int)h << 16);
}

// ---------------- weight prep (unchanged): fuse lin+l1, B-frag swizzle ----------------
__global__ void wprep_kernel(const float* __restrict__ w_lin, const float* __restrict__ b_lin,
                             const float* __restrict__ w1, const float* __restrict__ b1,
                             const float* __restrict__ w2, const float* __restrict__ w3,
                             u16* __restrict__ wfrag1, u16* __restrict__ wfrag2,
                             u16* __restrict__ wfrag3, float* __restrict__ b_eff) {
    int e = blockIdx.x * blockDim.x + threadIdx.x;
    if (e < 12288) {
        int fi = e >> 9, r = e & 511, lane = r >> 3, j = r & 7;
        int kk = fi >> 2, nt = fi & 3;
        int k = kk * 32 + (lane >> 4) * 8 + j;
        int n = nt * 16 + (lane & 15);
        float val;
        if (k < 128) {
            float s = 0.f;
            for (int jj = 0; jj < 64; jj++) s += w_lin[k * 64 + jj] * w1[jj * 64 + n];
            val = s;
        } else {
            val = w1[(k - 64) * 64 + n];
        }
        wfrag1[e] = f2bf(val);
    } else if (e < 12288 + 2048) {
        int e2 = e - 12288;
        int fi = e2 >> 9, lane = (e2 >> 3) & 63, j = e2 & 7;
        int kk = fi >> 1, nt = fi & 1;
        int k = kk * 32 + (lane >> 4) * 8 + j;
        int n = nt * 16 + (lane & 15);
        wfrag2[e2] = f2bf(w2[k * 32 + n]);
    } else if (e < 12288 + 2048 + 512) {
        int e3 = e - 12288 - 2048;
        int lane = e3 >> 3, j = e3 & 7;
        int k = (lane >> 4) * 8 + j;
        int n = lane & 15;
        wfrag3[e3] = f2bf(w3[k * 16 + n]);
    } else if (e < 12288 + 2048 + 512 + 64) {
        int n = e - 12288 - 2048 - 512;
        float s = b1[n];
        for (int jj = 0; jj < 64; jj++) s += b_lin[jj] * w1[jj * 64 + n];
        b_eff[n] = s;
    }
}

// ---------------- dense main: reg-staged bf16 tile, full staging MLP ----------------
// grid: 8192 blocks; block nb -> b = nb>>12, r = (nb&4095)>>3, c0 = (nb&7)<<6.
__global__ __launch_bounds__(256, 6) void fbseg_dense_kernel(
    const float* __restrict__ p0, const float* __restrict__ p1,
    const float* __restrict__ fl,
    const u16* __restrict__ wfrag1, const u16* __restrict__ wfrag2,
    const u16* __restrict__ wfrag3, const float* __restrict__ b_eff,
    const float* __restrict__ b2, const float* __restrict__ b3,
    const float* __restrict__ w4, const float* __restrict__ b4,
    float* __restrict__ score)
{
    __shared__ __align__(16) u16 feat[192 * CSTR];  // 26880 B -> 6 blocks/CU

    const int tid  = threadIdx.x;
    const int wv   = tid >> 6;
    const int lane = tid & 63;
    const int lr   = lane & 15;
    const int lq   = lane >> 4;
    const int m0w  = wv * 16;
    const int col  = m0w + lr;

    const int nb = blockIdx.x;
    const int b  = nb >> 12;
    const int r  = (nb & 4095) >> 3;
    const int c0 = (nb & 7) << 6;

    // ---- staging: wave wv covers channels [48wv, 48wv+48) for all 64 px ----
    // Phase A: issue ALL 12 dwordx4 loads (48 VGPR payload, one latency trip).
    // Bases are wave-uniform -> readfirstlane pins them to SGPRs; single shared
    // 32-bit lane offset (q*MAPHW + lr*4 floats).
    {
        const int q  = lq;
        const int p4 = lr * 4;
        const unsigned laneoff = (unsigned)(q * MAPHW + p4);  // floats
        f32x4 v[12];
        #pragma unroll
        for (int s = 0; s < 12; s++) {
            const int C4s = __builtin_amdgcn_readfirstlane(wv * 48 + s * 4);
            const float* mp = (C4s < 64) ? p0 : ((C4s < 128) ? p1 : fl);
            const float* bs = mp + (size_t)b * ((size_t)64 * MAPHW)
                            + (size_t)(C4s & 63) * MAPHW
                            + (size_t)r * MAPW + (size_t)c0;
            v[s] = *(const f32x4*)(bs + laneoff);
        }
        // Phase B: pack to bf16 (hw RNE, 2 floats/instr) + LDS write.
        #pragma unroll
        for (int s = 0; s < 12; s++) {
            const int C = wv * 48 + s * 4 + q;
            u32 lo, hi;
            asm("v_cvt_pk_bf16_f32 %0, %1, %2" : "=v"(lo) : "v"(v[s][0]), "v"(v[s][1]));
            asm("v_cvt_pk_bf16_f32 %0, %1, %2" : "=v"(hi) : "v"(v[s][2]), "v"(v[s][3]));
            u32* dst = (u32*)(feat + C * CSTR + p4);  // dword-aligned
            dst[0] = lo;
            dst[1] = hi;
        }
    }
    __syncthreads();

    // ---- layer 1: K=192 -> N=64 ; A read directly as bf16 ----
    f32x4 acc1[4] = {};
    #pragma unroll
    for (int kk = 0; kk < 6; kk++) {
        sh8 a;
        u16* ap = (u16*)&a;
        #pragma unroll
        for (int j = 0; j < 8; j++)
            ap[j] = feat[(kk * 32 + lq * 8 + j) * CSTR + col];
        #pragma unroll
        for (int nt = 0; nt < 4; nt++) {
            sh8 bfr = *(const sh8*)(wfrag1 + ((kk * 4 + nt) * 64 + lane) * 8);
            acc1[nt] = __builtin_amdgcn_mfma_f32_16x16x32_bf16(a, bfr, acc1[nt], 0, 0, 0);
        }
    }
    __syncthreads();  // feat dead for ALL waves; reuse as per-wave H scratch

    u16* Hbase = feat + wv * HWAVE;
    u16* H1w = Hbase;
    u16* H2w = Hbase + 16 * H1S;
    u16* H3w = Hbase + 16 * H1S + 16 * H2S;

    #pragma unroll
    for (int nt = 0; nt < 4; nt++) {
        const int n = nt * 16 + lr;
        const float bias = b_eff[n];
        #pragma unroll
        for (int rg = 0; rg < 4; rg++) {
            const int row = lq * 4 + rg;
            H1w[row * H1S + n] = f2bf(gelu_f(acc1[nt][rg] + bias));
        }
    }

    // layer 2: K=64 -> N=32
    f32x4 acc2[2] = {};
    #pragma unroll
    for (int kk = 0; kk < 2; kk++) {
        sh8 a = *(const sh8*)&H1w[lr * H1S + kk * 32 + lq * 8];
        #pragma unroll
        for (int nt = 0; nt < 2; nt++) {
            sh8 bfr = *(const sh8*)(wfrag2 + ((kk * 2 + nt) * 64 + lane) * 8);
            acc2[nt] = __builtin_amdgcn_mfma_f32_16x16x32_bf16(a, bfr, acc2[nt], 0, 0, 0);
        }
    }
    #pragma unroll
    for (int nt = 0; nt < 2; nt++) {
        const int n = nt * 16 + lr;
        const float bias = b2[n];
        #pragma unroll
        for (int rg = 0; rg < 4; rg++) {
            const int row = lq * 4 + rg;
            H2w[row * H2S + n] = f2bf(gelu_f(acc2[nt][rg] + bias));
        }
    }

    // layer 3: K=32 -> N=16
    f32x4 acc3 = {};
    {
        sh8 a = *(const sh8*)&H2w[lr * H2S + lq * 8];
        sh8 bfr = *(const sh8*)(wfrag3 + lane * 8);
        acc3 = __builtin_amdgcn_mfma_f32_16x16x32_bf16(a, bfr, acc3, 0, 0, 0);
    }
    {
        const float bias = b3[lr];
        #pragma unroll
        for (int rg = 0; rg < 4; rg++) {
            const int row = lq * 4 + rg;
            H3w[row * H3S + lr] = f2bf(gelu_f(acc3[rg] + bias));
        }
    }

    // layer 4 + sigmoid: lanes 0..15 finish one pixel each, write score map
    if (lane < 16) {
        float s = b4[0];
        #pragma unroll
        for (int k = 0; k < 16; k++) s = fmaf(bf2f(H3w[lane * H3S + k]), w4[k], s);
        score[(size_t)b * MAPHW + (size_t)r * MAPW + (size_t)(c0 + m0w + lane)] =
            1.0f / (1.0f + expf(-s));
    }
}

// ---------------- per-point resolve: score map is 2 MB -> L2-resident ----------------
__global__ void lookup_kernel(const int* __restrict__ lidar, const int* __restrict__ radar,
                              const float* __restrict__ score, float* __restrict__ out) {
    int p = blockIdx.x * blockDim.x + threadIdx.x;
    if (p >= NTOT) return;
    int b = p / NPTS;
    int i = p - b * NPTS;
    int r, c;
    if (i < NLID) {
        const int* cd = lidar + (size_t)(b * NLID + i) * 3;
        r = cd[1]; c = cd[2];
    } else {
        const int* cd = radar + (size_t)(b * NRAD + (i - NLID)) * 3;
        r = cd[1]; c = cd[2];
    }
    out[p] = score[(size_t)b * MAPHW + (size_t)r * MAPW + (size_t)c];
}

extern "C" void kernel_launch(void* const* d_in, const int* in_sizes, int n_in,
                              void* d_out, int out_size, void* d_ws, size_t ws_size,
                              hipStream_t stream) {
    const float* p0    = (const float*)d_in[0];
    const float* p1    = (const float*)d_in[1];
    const float* fl    = (const float*)d_in[2];
    const int*   lidar = (const int*)d_in[3];
    const int*   radar = (const int*)d_in[4];
    const float* w_lin = (const float*)d_in[5];
    const float* b_lin = (const float*)d_in[6];
    const float* w1    = (const float*)d_in[7];
    const float* b1    = (const float*)d_in[8];
    const float* w2    = (const float*)d_in[9];
    const float* b2    = (const float*)d_in[10];
    const float* w3    = (const float*)d_in[11];
    const float* b3    = (const float*)d_in[12];
    const float* w4    = (const float*)d_in[13];
    const float* b4    = (const float*)d_in[14];
    float* out = (float*)d_out;

    // ws layout: score_map (2 MB) | wfrag1 | wfrag2 | wfrag3 | b_eff
    char* ws = (char*)d_ws;
    float* score = (float*)ws;
    char* wbase  = ws + (size_t)2 * MAPHW * sizeof(float);
    u16*  wfrag1 = (u16*)wbase;
    u16*  wfrag2 = (u16*)(wbase + 12288 * 2);
    u16*  wfrag3 = (u16*)(wbase + (12288 + 2048) * 2);
    float* b_eff = (float*)(wbase + (12288 + 2048 + 512) * 2);

    hipLaunchKernelGGL(wprep_kernel, dim3((14912 + 255) / 256), dim3(256), 0, stream,
                       w_lin, b_lin, w1, b1, w2, w3, wfrag1, wfrag2, wfrag3, b_eff);
    hipLaunchKernelGGL(fbseg_dense_kernel, dim3(NTILES), dim3(256), 0, stream,
                       p0, p1, fl, wfrag1, wfrag2, wfrag3, b_eff, b2, b3, w4, b4, score);
    hipLaunchKernelGGL(lookup_kernel, dim3((NTOT + 255) / 256), dim3(256), 0, stream,
                       lidar, radar, score, out);
}